// Round 3
// baseline (621.219 us; speedup 1.0000x reference)
//
#include <hip/hip_runtime.h>
#include <cstdint>
#include <cstddef>

typedef unsigned short u16;
typedef __bf16 bf16x8 __attribute__((ext_vector_type(8)));
typedef unsigned short u16x8 __attribute__((ext_vector_type(8)));
typedef float   f32x4 __attribute__((ext_vector_type(4)));

#define D_MODEL 1024
#define NF      256      // num random features (M)
#define DEPTH   512
#define SEQ     4096
#define ROWS    16384    // B*L = 4*4096
#define HROWS   32768    // ROWS * NUM_HEADS (Q viewed as 32768 x 512)

// scale = 512^-0.25 ; folded into proj. 0.5*scale^2 used for diag.
#define QK_SCALE      0.21022410381342864f
#define HALF_SCALE2   0.022097086912079608f

__device__ __forceinline__ u16 f2bf(float f) {
  union { float f; uint32_t u; } x; x.f = f;
  uint32_t r = x.u + 0x7FFFu + ((x.u >> 16) & 1u);
  return (u16)(r >> 16);
}
__device__ __forceinline__ float bf2f(u16 u) {
  union { uint32_t u; float f; } x; x.u = ((uint32_t)u) << 16;
  return x.f;
}

// async global->LDS, 16B per lane; LDS dest = wave-uniform base + lane*16B.
__device__ __forceinline__ void gload16(const u16* g, u16* l) {
  __builtin_amdgcn_global_load_lds((const __attribute__((address_space(1))) void*)g,
                                   (__attribute__((address_space(3))) void*)l,
                                   16, 0, 0);
}

// ---------------- weight prep kernels ----------------

// W (1024x1024 f32) -> W^T bf16 ([N][K] layout for gemm_bt). blockIdx.z picks matrix.
__global__ void transpose4_kernel(const float* __restrict__ w0, const float* __restrict__ w1,
                                  const float* __restrict__ w2, const float* __restrict__ w3,
                                  u16* __restrict__ o0, u16* __restrict__ o1,
                                  u16* __restrict__ o2, u16* __restrict__ o3) {
  __shared__ float tile[32][33];
  int z = blockIdx.z;
  const float* src = (z == 0) ? w0 : (z == 1) ? w1 : (z == 2) ? w2 : w3;
  u16* dst         = (z == 0) ? o0 : (z == 1) ? o1 : (z == 2) ? o2 : o3;
  int bx = blockIdx.x * 32, by = blockIdx.y * 32;
  int tx = threadIdx.x, ty = threadIdx.y;  // block (32,8)
#pragma unroll
  for (int r = ty; r < 32; r += 8) tile[r][tx] = src[(size_t)(by + r) * D_MODEL + bx + tx];
  __syncthreads();
#pragma unroll
  for (int r = ty; r < 32; r += 8)
    dst[(size_t)(bx + r) * D_MODEL + by + tx] = f2bf(tile[tx][r]);
}

// proj (256x512 f32) -> bf16 with qk scale folded in. 32768 threads, 4 elems each.
__global__ void projcvt_kernel(const float4* __restrict__ p, ushort4* __restrict__ o) {
  int i = blockIdx.x * 256 + threadIdx.x;
  float4 a = p[i];
  o[i] = make_ushort4(f2bf(a.x * QK_SCALE), f2bf(a.y * QK_SCALE),
                      f2bf(a.z * QK_SCALE), f2bf(a.w * QK_SCALE));
}

// ---------------- GEMM: C[M][N] = A[M][K] @ B[N][K]^T + bias ----------------
// 128x128 tile, BK=32, 256 threads = 4 waves in 2x2 grid, each wave 64x64 via
// 4x4 mfma_f32_16x16x32_bf16. B staged via global_load_lds width=16.
// A staged either via global_load_lds (bf16 input) or fp32 load + convert +
// lane-ordered ds_write_b128 (AFP32: fused input conversion, conflict-free).
// Grid: blockIdx.x = bm (fast) so the 8 bn-blocks sharing an A-tile land on
// the SAME XCD (linear%8 == bm%8) -> A fetched once, B L2-resident.
template <bool BF16OUT, bool AFP32>
__global__ __launch_bounds__(256) void gemm_bt_kernel(
    const void* __restrict__ Av, const u16* __restrict__ B, void* __restrict__ Cv,
    const float* __restrict__ bias, int K, int N) {
  __shared__ __align__(16) u16 As[128 * 32];
  __shared__ __align__(16) u16 Bs[128 * 32];
  const int tid  = threadIdx.x;
  const int lane = tid & 63;
  const int wave = tid >> 6;
  const int wm = wave >> 1, wn = wave & 1;
  const int quad = lane >> 4, l15 = lane & 15;
  const int bm = blockIdx.x, bn = blockIdx.y;   // bm fast -> XCD locality
  const u16* Bb = (const u16*)B + (size_t)bn * 128 * K;

  // Lane l covers row (chunk*16 + l/4), col elems (l%4)*8..+8; data lands at
  // ldsbase + l*16B == row-major [row][col] exactly (DMA order == write order).
  const int srow = lane >> 2;
  const int scol = (lane & 3) * 8;
  const u16* Bg0 = Bb + (size_t)(wave * 32 + srow) * K + scol;
  const u16* Bg1 = Bg0 + (size_t)16 * K;
  u16* lA0 = As + wave * 1024;
  u16* lA1 = lA0 + 512;
  u16* lB0 = Bs + wave * 1024;
  u16* lB1 = lB0 + 512;

  // bf16-A DMA sources / fp32-A load sources
  const u16*   Ag0  = nullptr; const u16*   Ag1  = nullptr;
  const float* Af0  = nullptr; const float* Af1  = nullptr;
  if (AFP32) {
    const float* Ab = (const float*)Av + (size_t)bm * 128 * K;
    Af0 = Ab + (size_t)(wave * 32 + srow) * K + scol;
    Af1 = Af0 + (size_t)16 * K;
  } else {
    const u16* Ab = (const u16*)Av + (size_t)bm * 128 * K;
    Ag0 = Ab + (size_t)(wave * 32 + srow) * K + scol;
    Ag1 = Ag0 + (size_t)16 * K;
  }
  u16* wA0 = As + wave * 1024 + lane * 8;   // lane-ordered 16B slot (conflict-free)
  u16* wA1 = wA0 + 512;

  f32x4 acc[4][4] = {};

  for (int k0 = 0; k0 < K; k0 += 32) {
    __syncthreads();               // previous iter's LDS reads complete
    if (AFP32) {
      // fp32 A loads first (oldest in vmcnt queue), then B DMAs behind them.
      float4 p00 = *(const float4*)(Af0 + k0);
      float4 p01 = *(const float4*)(Af0 + k0 + 4);
      float4 p10 = *(const float4*)(Af1 + k0);
      float4 p11 = *(const float4*)(Af1 + k0 + 4);
      gload16(Bg0 + k0, lB0);
      gload16(Bg1 + k0, lB1);
      u16x8 c0, c1;
      c0[0]=f2bf(p00.x); c0[1]=f2bf(p00.y); c0[2]=f2bf(p00.z); c0[3]=f2bf(p00.w);
      c0[4]=f2bf(p01.x); c0[5]=f2bf(p01.y); c0[6]=f2bf(p01.z); c0[7]=f2bf(p01.w);
      c1[0]=f2bf(p10.x); c1[1]=f2bf(p10.y); c1[2]=f2bf(p10.z); c1[3]=f2bf(p10.w);
      c1[4]=f2bf(p11.x); c1[5]=f2bf(p11.y); c1[6]=f2bf(p11.z); c1[7]=f2bf(p11.w);
      *(u16x8*)wA0 = c0;
      *(u16x8*)wA1 = c1;
    } else {
      gload16(Ag0 + k0, lA0);
      gload16(Ag1 + k0, lA1);
      gload16(Bg0 + k0, lB0);
      gload16(Bg1 + k0, lB1);
    }
    __syncthreads();               // drains vmcnt/lgkmcnt -> tiles complete
    bf16x8 af[4], bfr[4];
#pragma unroll
    for (int mt = 0; mt < 4; mt++)
      af[mt] = *(const bf16x8*)&As[(wm * 64 + mt * 16 + l15) * 32 + quad * 8];
#pragma unroll
    for (int nt = 0; nt < 4; nt++)
      bfr[nt] = *(const bf16x8*)&Bs[(wn * 64 + nt * 16 + l15) * 32 + quad * 8];
#pragma unroll
    for (int mt = 0; mt < 4; mt++)
#pragma unroll
      for (int nt = 0; nt < 4; nt++)
        acc[mt][nt] = __builtin_amdgcn_mfma_f32_16x16x32_bf16(af[mt], bfr[nt], acc[mt][nt], 0, 0, 0);
  }

  // epilogue: C/D layout col = lane&15, row = quad*4 + reg  [m89/m91 verified]
  const int rbase = bm * 128 + wm * 64 + quad * 4;
  const int cbase = bn * 128 + wn * 64 + l15;
#pragma unroll
  for (int nt = 0; nt < 4; nt++) {
    int col = cbase + nt * 16;
    float bvad = bias ? bias[col] : 0.0f;
#pragma unroll
    for (int mt = 0; mt < 4; mt++) {
#pragma unroll
      for (int r = 0; r < 4; r++) {
        int row = rbase + mt * 16 + r;
        float v = acc[mt][nt][r] + bvad;
        if (BF16OUT) ((u16*)Cv)[(size_t)row * N + col] = f2bf(v);
        else         ((float*)Cv)[(size_t)row * N + col] = v;
      }
    }
  }
}

// ---------------- diag: 0.5*scale^2*||row||^2 over Qb/Kb rows of 512 ----------------
// grid 16384 x 256: 4 waves/block, one row per wave; rows 0..32767 -> Q, 32768.. -> K.
__global__ void diag_kernel(const u16* __restrict__ Qb, const u16* __restrict__ Kb,
                            float* __restrict__ dq, float* __restrict__ dk) {
  const int wave = threadIdx.x >> 6, lane = threadIdx.x & 63;
  int row = blockIdx.x * 4 + wave;
  const u16* src; float* dst; int r;
  if (row < HROWS) { src = Qb; dst = dq; r = row; }
  else             { src = Kb; dst = dk; r = row - HROWS; }
  const ushort4* p = (const ushort4*)(src + (size_t)r * DEPTH);
  ushort4 u0 = p[lane * 2], u1 = p[lane * 2 + 1];
  float s = 0.f, f;
  f = bf2f(u0.x); s += f * f; f = bf2f(u0.y); s += f * f;
  f = bf2f(u0.z); s += f * f; f = bf2f(u0.w); s += f * f;
  f = bf2f(u1.x); s += f * f; f = bf2f(u1.y); s += f * f;
  f = bf2f(u1.z); s += f * f; f = bf2f(u1.w); s += f * f;
#pragma unroll
  for (int o = 32; o; o >>= 1) s += __shfl_xor(s, o);
  if (lane == 0) dst[r] = s * HALF_SCALE2;
}

// ---------------- global max of k_dash per (batch,head) ----------------
// stage 1: grid 512 = 8 groups * 64 s-blocks (64 s each); one partial per block.
__global__ void maxk_part_kernel(const float* __restrict__ kd, float* __restrict__ partials) {
  int g = blockIdx.x >> 6;   // b*2+h
  int sb = blockIdx.x & 63;
  int b = g >> 1, h = g & 1;
  int tid = threadIdx.x;
  float mx = -3.4e38f;
  for (int j = 0; j < 64; j++) {
    int s = sb * 64 + j;
    int row = b * 8192 + s * 2 + h;
    mx = fmaxf(mx, kd[(size_t)row * NF + tid]);
  }
#pragma unroll
  for (int o = 32; o; o >>= 1) mx = fmaxf(mx, __shfl_xor(mx, o));
  __shared__ float wmax[4];
  if ((tid & 63) == 0) wmax[tid >> 6] = mx;
  __syncthreads();
  if (tid == 0)
    partials[blockIdx.x] = fmaxf(fmaxf(wmax[0], wmax[1]), fmaxf(wmax[2], wmax[3]));
}

// stage 2: 8 blocks x 64 lanes.
__global__ void maxk_final_kernel(const float* __restrict__ partials, float* __restrict__ mxk) {
  float v = partials[blockIdx.x * 64 + threadIdx.x];
#pragma unroll
  for (int o = 32; o; o >>= 1) v = fmaxf(v, __shfl_xor(v, o));
  if (threadIdx.x == 0) mxk[blockIdx.x] = v;
}

// ---------------- fused exp + 4x4 batch-contraction attention ----------------
// One block per (s,h). q',k' via online exp; A = q'k'^T (4x4); out = (A@v)/rowsum(A).
// Writes concat bf16 at flat s*4096 + h*2048 + batch*512 + d (the reshape quirk).
__global__ __launch_bounds__(256) void attn_kernel(
    const float* __restrict__ qd, const float* __restrict__ kd,
    const float* __restrict__ diagq, const float* __restrict__ diagk,
    const float* __restrict__ mxk, const u16* __restrict__ Vb,
    u16* __restrict__ concat) {
  int s = blockIdx.x >> 1, h = blockIdx.x & 1;
  int t = threadIdx.x;           // 256 threads; thread t <-> feature m = t
  int wave = t >> 6, lane = t & 63;
  __shared__ float qp[4][256], kp[4][256];
  __shared__ float As[4][4];
  __shared__ float wred[4][4];   // [wave][b]
  __shared__ float mqs[4];

  float qv[4], kv[4];
  int rows[4];
#pragma unroll
  for (int b = 0; b < 4; b++) {
    int r = b * 8192 + s * 2 + h;
    rows[b] = r;
    qv[b] = qd[(size_t)r * NF + t];
    kv[b] = kd[(size_t)r * NF + t];
  }
  // per-row max of q_dash (max over m == over the 256 threads)
#pragma unroll
  for (int b = 0; b < 4; b++) {
    float v = qv[b];
#pragma unroll
    for (int o = 32; o; o >>= 1) v = fmaxf(v, __shfl_xor(v, o));
    if (lane == 0) wred[wave][b] = v;
  }
  __syncthreads();
  if (t < 4) mqs[t] = fmaxf(fmaxf(wred[0][t], wred[1][t]), fmaxf(wred[2][t], wred[3][t]));
  __syncthreads();
#pragma unroll
  for (int b = 0; b < 4; b++) {
    qp[b][t] = __expf(qv[b] - diagq[rows[b]] - mqs[b]) + 1e-6f;
    kp[b][t] = __expf(kv[b] - diagk[rows[b]] - mxk[b * 2 + h]) + 1e-6f;
  }
  __syncthreads();
  // A[i][j] = sum_m qp[i][m]*kp[j][m]; wave i computes row i.
  {
    int i = wave;
    float p0 = 0, p1 = 0, p2 = 0, p3 = 0;
    for (int m = lane; m < 256; m += 64) {
      float q = qp[i][m];
      p0 += q * kp[0][m]; p1 += q * kp[1][m];
      p2 += q * kp[2][m]; p3 += q * kp[3][m];
    }
#pragma unroll
    for (int o = 32; o; o >>= 1) {
      p0 += __shfl_xor(p0, o); p1 += __shfl_xor(p1, o);
      p2 += __shfl_xor(p2, o); p3 += __shfl_xor(p3, o);
    }
    if (lane == 0) { As[i][0] = p0; As[i][1] = p1; As[i][2] = p2; As[i][3] = p3; }
  }
  __syncthreads();
  float a00 = As[0][0], a01 = As[0][1], a02 = As[0][2], a03 = As[0][3];
  float a10 = As[1][0], a11 = As[1][1], a12 = As[1][2], a13 = As[1][3];
  float a20 = As[2][0], a21 = As[2][1], a22 = As[2][2], a23 = As[2][3];
  float a30 = As[3][0], a31 = As[3][1], a32 = As[3][2], a33 = As[3][3];
  float n0 = 1.f / (a00 + a01 + a02 + a03);
  float n1 = 1.f / (a10 + a11 + a12 + a13);
  float n2 = 1.f / (a20 + a21 + a22 + a23);
  float n3 = 1.f / (a30 + a31 + a32 + a33);
  size_t obase = (size_t)s * 4096 + (size_t)h * 2048;
#pragma unroll
  for (int dp = 0; dp < 2; dp++) {
    int d = t + dp * 256;
    float v0 = bf2f(Vb[((size_t)(0 * SEQ + s)) * D_MODEL + h * DEPTH + d]);
    float v1 = bf2f(Vb[((size_t)(1 * SEQ + s)) * D_MODEL + h * DEPTH + d]);
    float v2 = bf2f(Vb[((size_t)(2 * SEQ + s)) * D_MODEL + h * DEPTH + d]);
    float v3 = bf2f(Vb[((size_t)(3 * SEQ + s)) * D_MODEL + h * DEPTH + d]);
    concat[obase + 0 * 512 + d] = f2bf((a00 * v0 + a01 * v1 + a02 * v2 + a03 * v3) * n0);
    concat[obase + 1 * 512 + d] = f2bf((a10 * v0 + a11 * v1 + a12 * v2 + a13 * v3) * n1);
    concat[obase + 2 * 512 + d] = f2bf((a20 * v0 + a21 * v1 + a22 * v2 + a23 * v3) * n2);
    concat[obase + 3 * 512 + d] = f2bf((a30 * v0 + a31 * v1 + a32 * v2 + a33 * v3) * n3);
  }
}

// ---------------- launch ----------------
extern "C" void kernel_launch(void* const* d_in, const int* in_sizes, int n_in,
                              void* d_out, int out_size, void* d_ws, size_t ws_size,
                              hipStream_t stream) {
  (void)in_sizes; (void)n_in; (void)out_size; (void)ws_size;
  const float* query = (const float*)d_in[0];
  const float* key   = (const float*)d_in[1];
  const float* value = (const float*)d_in[2];
  // d_in[3] = mask (unused by the reference computation)
  const float* Wq = (const float*)d_in[4];
  const float* bq = (const float*)d_in[5];
  const float* Wk = (const float*)d_in[6];
  const float* bk = (const float*)d_in[7];
  const float* Wv = (const float*)d_in[8];
  const float* bv = (const float*)d_in[9];
  const float* Wo = (const float*)d_in[10];
  const float* bo = (const float*)d_in[11];
  const float* proj = (const float*)d_in[12];
  float* out = (float*)d_out;

  char* w = (char*)d_ws;
  size_t o = 0;
  auto take = [&](size_t b) { void* p = w + o; o += (b + 255) & ~(size_t)255; return p; };
  u16* Wqt   = (u16*)take(2097152);
  u16* Wkt   = (u16*)take(2097152);
  u16* Wvt   = (u16*)take(2097152);
  u16* Wot   = (u16*)take(2097152);
  u16* projb = (u16*)take(262144);
  u16* Qb    = (u16*)take(33554432);    // 32768 x 512 bf16
  u16* Kb    = (u16*)take(33554432);
  u16* Vb    = (u16*)take(33554432);
  float* qd  = (float*)take(33554432);  // 32768 x 256 f32
  float* kd  = (float*)take(33554432);
  u16* concat = (u16*)take(33554432);   // 16384 x 1024 bf16
  float* diagq    = (float*)take(131072);
  float* diagk    = (float*)take(131072);
  float* partials = (float*)take(2048);
  float* mxk      = (float*)take(64);
  // peak ws use ~201 MB

  transpose4_kernel<<<dim3(32, 32, 4), dim3(32, 8), 0, stream>>>(Wq, Wk, Wv, Wo,
                                                                 Wqt, Wkt, Wvt, Wot);
  projcvt_kernel<<<128, 256, 0, stream>>>((const float4*)proj, (ushort4*)projb);

  // QKV projections: fp32 A fused conversion, bm on x for XCD L2 locality.
  gemm_bt_kernel<true, true><<<dim3(128, 8), 256, 0, stream>>>(query, Wqt, Qb, bq, 1024, 1024);
  gemm_bt_kernel<true, true><<<dim3(128, 8), 256, 0, stream>>>(key,   Wkt, Kb, bk, 1024, 1024);
  gemm_bt_kernel<true, true><<<dim3(128, 8), 256, 0, stream>>>(value, Wvt, Vb, bv, 1024, 1024);

  diag_kernel<<<16384, 256, 0, stream>>>(Qb, Kb, diagq, diagk);

  gemm_bt_kernel<false, false><<<dim3(256, 2), 256, 0, stream>>>(Qb, projb, qd, nullptr, 512, 256);
  gemm_bt_kernel<false, false><<<dim3(256, 2), 256, 0, stream>>>(Kb, projb, kd, nullptr, 512, 256);

  maxk_part_kernel<<<512, 256, 0, stream>>>(kd, partials);
  maxk_final_kernel<<<8, 64, 0, stream>>>(partials, mxk);

  attn_kernel<<<8192, 256, 0, stream>>>(qd, kd, diagq, diagk, mxk, Vb, concat);

  gemm_bt_kernel<false, false><<<dim3(128, 8), 256, 0, stream>>>(concat, Wot, out, bo, 1024, 1024);
}

// Round 4
// 593.814 us; speedup vs baseline: 1.0462x; 1.0462x over previous
//
#include <hip/hip_runtime.h>
#include <cstdint>
#include <cstddef>

typedef unsigned short u16;
typedef __bf16 bf16x8 __attribute__((ext_vector_type(8)));
typedef unsigned short u16x8 __attribute__((ext_vector_type(8)));
typedef float   f32x4 __attribute__((ext_vector_type(4)));

#define D_MODEL 1024
#define NF      256      // num random features (M)
#define DEPTH   512
#define SEQ     4096
#define ROWS    16384    // B*L = 4*4096
#define HROWS   32768    // ROWS * NUM_HEADS (Q viewed as 32768 x 512)

// scale = 512^-0.25 ; folded into proj. 0.5*scale^2 used for diag.
#define QK_SCALE      0.21022410381342864f
#define HALF_SCALE2   0.022097086912079608f

__device__ __forceinline__ u16 f2bf(float f) {
  union { float f; uint32_t u; } x; x.f = f;
  uint32_t r = x.u + 0x7FFFu + ((x.u >> 16) & 1u);
  return (u16)(r >> 16);
}
__device__ __forceinline__ float bf2f(u16 u) {
  union { uint32_t u; float f; } x; x.u = ((uint32_t)u) << 16;
  return x.f;
}

// async global->LDS, 16B per lane; LDS dest = wave-uniform base + lane*16B.
__device__ __forceinline__ void gload16(const u16* g, u16* l) {
  __builtin_amdgcn_global_load_lds((const __attribute__((address_space(1))) void*)g,
                                   (__attribute__((address_space(3))) void*)l,
                                   16, 0, 0);
}

// ---------------- weight prep kernels ----------------

// W (1024x1024 f32) -> W^T bf16 ([N][K] layout for gemm_bt). blockIdx.z picks matrix.
__global__ void transpose4_kernel(const float* __restrict__ w0, const float* __restrict__ w1,
                                  const float* __restrict__ w2, const float* __restrict__ w3,
                                  u16* __restrict__ o0, u16* __restrict__ o1,
                                  u16* __restrict__ o2, u16* __restrict__ o3) {
  __shared__ float tile[32][33];
  int z = blockIdx.z;
  const float* src = (z == 0) ? w0 : (z == 1) ? w1 : (z == 2) ? w2 : w3;
  u16* dst         = (z == 0) ? o0 : (z == 1) ? o1 : (z == 2) ? o2 : o3;
  int bx = blockIdx.x * 32, by = blockIdx.y * 32;
  int tx = threadIdx.x, ty = threadIdx.y;  // block (32,8)
#pragma unroll
  for (int r = ty; r < 32; r += 8) tile[r][tx] = src[(size_t)(by + r) * D_MODEL + bx + tx];
  __syncthreads();
#pragma unroll
  for (int r = ty; r < 32; r += 8)
    dst[(size_t)(bx + r) * D_MODEL + by + tx] = f2bf(tile[tx][r]);
}

// proj (256x512 f32) -> bf16 with qk scale folded in. 32768 threads, 4 elems each.
__global__ void projcvt_kernel(const float4* __restrict__ p, ushort4* __restrict__ o) {
  int i = blockIdx.x * 256 + threadIdx.x;
  float4 a = p[i];
  o[i] = make_ushort4(f2bf(a.x * QK_SCALE), f2bf(a.y * QK_SCALE),
                      f2bf(a.z * QK_SCALE), f2bf(a.w * QK_SCALE));
}

// ---------------- GEMM: C[M][N] = A[M][K] @ B[N][K]^T + bias ----------------
// 128x128 tile, BK=32, 256 threads = 4 waves in 2x2 grid, each wave 64x64 via
// 4x4 mfma_f32_16x16x32_bf16.
//
// Double-buffered LDS with prefetch-ahead: tile k+1's loads are issued AFTER
// the last barrier of iter k, so the compiler's vmcnt(0)-before-barrier drain
// at iter k+1 only waits (latency - compute_phase). bf16-A path is a single
// barrier per iter; fp32-A path (fused input conversion) needs a second
// barrier for the cooperative ds_write, but prefetches are issued after it.
//
// LDS chunk swizzle: the tile row stride is 64 B, so identity placement makes
// b128 reads 8-way bank-conflicted. Lane l stages global chunk
// c = ((l&3)-(l>>3))&3 of row l>>2 into dense slot l (DMA-compatible);
// reads use slot (quad + (l15>>1))&3 -> exactly 2 lanes/bank-group (free).
//
// Grid: blockIdx.x = bm (fast) so the bn-blocks sharing an A-tile land on the
// same XCD (linear%8 == bm%8): A fetched from HBM once, B L2-resident.
template <bool BF16OUT, bool AFP32>
__global__ __launch_bounds__(256) void gemm_bt_kernel(
    const void* __restrict__ Av, const u16* __restrict__ B, void* __restrict__ Cv,
    const float* __restrict__ bias, int K, int N) {
  __shared__ __align__(16) u16 As[2][128 * 32];
  __shared__ __align__(16) u16 Bs[2][128 * 32];
  const int tid  = threadIdx.x;
  const int lane = tid & 63;
  const int wave = tid >> 6;
  const int wm = wave >> 1, wn = wave & 1;
  const int quad = lane >> 4, l15 = lane & 15;
  const int bm = blockIdx.x, bn = blockIdx.y;   // bm fast -> XCD locality

  const int srow   = lane >> 2;
  const int schunk = ((lane & 3) - (lane >> 3)) & 3;   // swizzled chunk for lane
  const int scol   = schunk * 8;

  const u16* Bb  = B + (size_t)bn * 128 * K;
  const u16* Bg0 = Bb + (size_t)(wave * 32 + srow) * K + scol;
  const u16* Bg1 = Bg0 + (size_t)16 * K;

  const float* Af0 = nullptr; const float* Af1 = nullptr;
  const u16*   Ag0 = nullptr; const u16*   Ag1 = nullptr;
  if (AFP32) {
    const float* Ab = (const float*)Av + (size_t)bm * 128 * K;
    Af0 = Ab + (size_t)(wave * 32 + srow) * K + scol;
    Af1 = Af0 + (size_t)16 * K;
  } else {
    const u16* Ab = (const u16*)Av + (size_t)bm * 128 * K;
    Ag0 = Ab + (size_t)(wave * 32 + srow) * K + scol;
    Ag1 = Ag0 + (size_t)16 * K;
  }

  const int sslot0 = wave * 1024 + lane * 8;   // dense lane slot (u16 units)
  const int sslot1 = sslot0 + 512;
  // swizzled read offset within a 16-row group (u16 units)
  const int ro = l15 * 32 + (((quad + (l15 >> 1)) & 3) * 8);

  f32x4 acc[4][4] = {};
  float4 p00, p01, p10, p11;

  // ---- prologue: tile 0 ----
  if (AFP32) {
    p00 = *(const float4*)(Af0);
    p01 = *(const float4*)(Af0 + 4);
    p10 = *(const float4*)(Af1);
    p11 = *(const float4*)(Af1 + 4);
  } else {
    gload16(Ag0, &As[0][wave * 1024]);
    gload16(Ag1, &As[0][wave * 1024 + 512]);
  }
  gload16(Bg0, &Bs[0][wave * 1024]);
  gload16(Bg1, &Bs[0][wave * 1024 + 512]);

  for (int k0 = 0; k0 < K; k0 += 32) {
    const int buf = (k0 >> 5) & 1;
    const int nxt = buf ^ 1;
    __syncthreads();   // tile(k) DMA/regs complete; readers of buf (iter k-2) done
    if (AFP32) {
      u16x8 c0, c1;
      c0[0]=f2bf(p00.x); c0[1]=f2bf(p00.y); c0[2]=f2bf(p00.z); c0[3]=f2bf(p00.w);
      c0[4]=f2bf(p01.x); c0[5]=f2bf(p01.y); c0[6]=f2bf(p01.z); c0[7]=f2bf(p01.w);
      c1[0]=f2bf(p10.x); c1[1]=f2bf(p10.y); c1[2]=f2bf(p10.z); c1[3]=f2bf(p10.w);
      c1[4]=f2bf(p11.x); c1[5]=f2bf(p11.y); c1[6]=f2bf(p11.z); c1[7]=f2bf(p11.w);
      *(u16x8*)&As[buf][sslot0] = c0;
      *(u16x8*)&As[buf][sslot1] = c1;
      __syncthreads();   // A tile visible (vmcnt already 0: nothing else in flight)
      if (k0 + 32 < K) {
        p00 = *(const float4*)(Af0 + k0 + 32);
        p01 = *(const float4*)(Af0 + k0 + 36);
        p10 = *(const float4*)(Af1 + k0 + 32);
        p11 = *(const float4*)(Af1 + k0 + 36);
        gload16(Bg0 + k0 + 32, &Bs[nxt][wave * 1024]);
        gload16(Bg1 + k0 + 32, &Bs[nxt][wave * 1024 + 512]);
      }
    } else {
      if (k0 + 32 < K) {
        gload16(Ag0 + k0 + 32, &As[nxt][wave * 1024]);
        gload16(Ag1 + k0 + 32, &As[nxt][wave * 1024 + 512]);
        gload16(Bg0 + k0 + 32, &Bs[nxt][wave * 1024]);
        gload16(Bg1 + k0 + 32, &Bs[nxt][wave * 1024 + 512]);
      }
    }
    // ---- compute tile k from buf (swizzled reads, 2-way conflict = free) ----
    bf16x8 af[4], bfr[4];
#pragma unroll
    for (int mt = 0; mt < 4; mt++)
      af[mt] = *(const bf16x8*)&As[buf][(wm * 4 + mt) * 512 + ro];
#pragma unroll
    for (int nt = 0; nt < 4; nt++)
      bfr[nt] = *(const bf16x8*)&Bs[buf][(wn * 4 + nt) * 512 + ro];
#pragma unroll
    for (int mt = 0; mt < 4; mt++)
#pragma unroll
      for (int nt = 0; nt < 4; nt++)
        acc[mt][nt] = __builtin_amdgcn_mfma_f32_16x16x32_bf16(af[mt], bfr[nt], acc[mt][nt], 0, 0, 0);
  }

  // epilogue: C/D layout col = lane&15, row = quad*4 + reg  [m89/m91 verified]
  const int rbase = bm * 128 + wm * 64 + quad * 4;
  const int cbase = bn * 128 + wn * 64 + l15;
#pragma unroll
  for (int nt = 0; nt < 4; nt++) {
    int col = cbase + nt * 16;
    float bvad = bias ? bias[col] : 0.0f;
#pragma unroll
    for (int mt = 0; mt < 4; mt++) {
#pragma unroll
      for (int r = 0; r < 4; r++) {
        int row = rbase + mt * 16 + r;
        float v = acc[mt][nt][r] + bvad;
        if (BF16OUT) ((u16*)Cv)[(size_t)row * N + col] = f2bf(v);
        else         ((float*)Cv)[(size_t)row * N + col] = v;
      }
    }
  }
}

// ---------------- diag: 0.5*scale^2*||row||^2 over Qb/Kb rows of 512 ----------------
// grid 16384 x 256: 4 waves/block, one row per wave; rows 0..32767 -> Q, 32768.. -> K.
__global__ void diag_kernel(const u16* __restrict__ Qb, const u16* __restrict__ Kb,
                            float* __restrict__ dq, float* __restrict__ dk) {
  const int wave = threadIdx.x >> 6, lane = threadIdx.x & 63;
  int row = blockIdx.x * 4 + wave;
  const u16* src; float* dst; int r;
  if (row < HROWS) { src = Qb; dst = dq; r = row; }
  else             { src = Kb; dst = dk; r = row - HROWS; }
  const ushort4* p = (const ushort4*)(src + (size_t)r * DEPTH);
  ushort4 u0 = p[lane * 2], u1 = p[lane * 2 + 1];
  float s = 0.f, f;
  f = bf2f(u0.x); s += f * f; f = bf2f(u0.y); s += f * f;
  f = bf2f(u0.z); s += f * f; f = bf2f(u0.w); s += f * f;
  f = bf2f(u1.x); s += f * f; f = bf2f(u1.y); s += f * f;
  f = bf2f(u1.z); s += f * f; f = bf2f(u1.w); s += f * f;
#pragma unroll
  for (int o = 32; o; o >>= 1) s += __shfl_xor(s, o);
  if (lane == 0) dst[r] = s * HALF_SCALE2;
}

// ---------------- global max of k_dash per (batch,head) ----------------
// stage 1: grid 512 = 8 groups * 64 s-blocks (64 s each); one partial per block.
__global__ void maxk_part_kernel(const float* __restrict__ kd, float* __restrict__ partials) {
  int g = blockIdx.x >> 6;   // b*2+h
  int sb = blockIdx.x & 63;
  int b = g >> 1, h = g & 1;
  int tid = threadIdx.x;
  float mx = -3.4e38f;
  for (int j = 0; j < 64; j++) {
    int s = sb * 64 + j;
    int row = b * 8192 + s * 2 + h;
    mx = fmaxf(mx, kd[(size_t)row * NF + tid]);
  }
#pragma unroll
  for (int o = 32; o; o >>= 1) mx = fmaxf(mx, __shfl_xor(mx, o));
  __shared__ float wmax[4];
  if ((tid & 63) == 0) wmax[tid >> 6] = mx;
  __syncthreads();
  if (tid == 0)
    partials[blockIdx.x] = fmaxf(fmaxf(wmax[0], wmax[1]), fmaxf(wmax[2], wmax[3]));
}

// stage 2: 8 blocks x 64 lanes.
__global__ void maxk_final_kernel(const float* __restrict__ partials, float* __restrict__ mxk) {
  float v = partials[blockIdx.x * 64 + threadIdx.x];
#pragma unroll
  for (int o = 32; o; o >>= 1) v = fmaxf(v, __shfl_xor(v, o));
  if (threadIdx.x == 0) mxk[blockIdx.x] = v;
}

// ---------------- fused exp + 4x4 batch-contraction attention ----------------
// One block per (s,h). q',k' via online exp; A = q'k'^T (4x4); out = (A@v)/rowsum(A).
// Writes concat bf16 at flat s*4096 + h*2048 + batch*512 + d (the reshape quirk).
__global__ __launch_bounds__(256) void attn_kernel(
    const float* __restrict__ qd, const float* __restrict__ kd,
    const float* __restrict__ diagq, const float* __restrict__ diagk,
    const float* __restrict__ mxk, const u16* __restrict__ Vb,
    u16* __restrict__ concat) {
  int s = blockIdx.x >> 1, h = blockIdx.x & 1;
  int t = threadIdx.x;           // 256 threads; thread t <-> feature m = t
  int wave = t >> 6, lane = t & 63;
  __shared__ float qp[4][256], kp[4][256];
  __shared__ float As[4][4];
  __shared__ float wred[4][4];   // [wave][b]
  __shared__ float mqs[4];

  float qv[4], kv[4];
  int rows[4];
#pragma unroll
  for (int b = 0; b < 4; b++) {
    int r = b * 8192 + s * 2 + h;
    rows[b] = r;
    qv[b] = qd[(size_t)r * NF + t];
    kv[b] = kd[(size_t)r * NF + t];
  }
  // per-row max of q_dash (max over m == over the 256 threads)
#pragma unroll
  for (int b = 0; b < 4; b++) {
    float v = qv[b];
#pragma unroll
    for (int o = 32; o; o >>= 1) v = fmaxf(v, __shfl_xor(v, o));
    if (lane == 0) wred[wave][b] = v;
  }
  __syncthreads();
  if (t < 4) mqs[t] = fmaxf(fmaxf(wred[0][t], wred[1][t]), fmaxf(wred[2][t], wred[3][t]));
  __syncthreads();
#pragma unroll
  for (int b = 0; b < 4; b++) {
    qp[b][t] = __expf(qv[b] - diagq[rows[b]] - mqs[b]) + 1e-6f;
    kp[b][t] = __expf(kv[b] - diagk[rows[b]] - mxk[b * 2 + h]) + 1e-6f;
  }
  __syncthreads();
  // A[i][j] = sum_m qp[i][m]*kp[j][m]; wave i computes row i.
  {
    int i = wave;
    float p0 = 0, p1 = 0, p2 = 0, p3 = 0;
    for (int m = lane; m < 256; m += 64) {
      float q = qp[i][m];
      p0 += q * kp[0][m]; p1 += q * kp[1][m];
      p2 += q * kp[2][m]; p3 += q * kp[3][m];
    }
#pragma unroll
    for (int o = 32; o; o >>= 1) {
      p0 += __shfl_xor(p0, o); p1 += __shfl_xor(p1, o);
      p2 += __shfl_xor(p2, o); p3 += __shfl_xor(p3, o);
    }
    if (lane == 0) { As[i][0] = p0; As[i][1] = p1; As[i][2] = p2; As[i][3] = p3; }
  }
  __syncthreads();
  float a00 = As[0][0], a01 = As[0][1], a02 = As[0][2], a03 = As[0][3];
  float a10 = As[1][0], a11 = As[1][1], a12 = As[1][2], a13 = As[1][3];
  float a20 = As[2][0], a21 = As[2][1], a22 = As[2][2], a23 = As[2][3];
  float a30 = As[3][0], a31 = As[3][1], a32 = As[3][2], a33 = As[3][3];
  float n0 = 1.f / (a00 + a01 + a02 + a03);
  float n1 = 1.f / (a10 + a11 + a12 + a13);
  float n2 = 1.f / (a20 + a21 + a22 + a23);
  float n3 = 1.f / (a30 + a31 + a32 + a33);
  size_t obase = (size_t)s * 4096 + (size_t)h * 2048;
#pragma unroll
  for (int dp = 0; dp < 2; dp++) {
    int d = t + dp * 256;
    float v0 = bf2f(Vb[((size_t)(0 * SEQ + s)) * D_MODEL + h * DEPTH + d]);
    float v1 = bf2f(Vb[((size_t)(1 * SEQ + s)) * D_MODEL + h * DEPTH + d]);
    float v2 = bf2f(Vb[((size_t)(2 * SEQ + s)) * D_MODEL + h * DEPTH + d]);
    float v3 = bf2f(Vb[((size_t)(3 * SEQ + s)) * D_MODEL + h * DEPTH + d]);
    concat[obase + 0 * 512 + d] = f2bf((a00 * v0 + a01 * v1 + a02 * v2 + a03 * v3) * n0);
    concat[obase + 1 * 512 + d] = f2bf((a10 * v0 + a11 * v1 + a12 * v2 + a13 * v3) * n1);
    concat[obase + 2 * 512 + d] = f2bf((a20 * v0 + a21 * v1 + a22 * v2 + a23 * v3) * n2);
    concat[obase + 3 * 512 + d] = f2bf((a30 * v0 + a31 * v1 + a32 * v2 + a33 * v3) * n3);
  }
}

// ---------------- launch ----------------
extern "C" void kernel_launch(void* const* d_in, const int* in_sizes, int n_in,
                              void* d_out, int out_size, void* d_ws, size_t ws_size,
                              hipStream_t stream) {
  (void)in_sizes; (void)n_in; (void)out_size; (void)ws_size;
  const float* query = (const float*)d_in[0];
  const float* key   = (const float*)d_in[1];
  const float* value = (const float*)d_in[2];
  // d_in[3] = mask (unused by the reference computation)
  const float* Wq = (const float*)d_in[4];
  const float* bq = (const float*)d_in[5];
  const float* Wk = (const float*)d_in[6];
  const float* bk = (const float*)d_in[7];
  const float* Wv = (const float*)d_in[8];
  const float* bv = (const float*)d_in[9];
  const float* Wo = (const float*)d_in[10];
  const float* bo = (const float*)d_in[11];
  const float* proj = (const float*)d_in[12];
  float* out = (float*)d_out;

  char* w = (char*)d_ws;
  size_t o = 0;
  auto take = [&](size_t b) { void* p = w + o; o += (b + 255) & ~(size_t)255; return p; };
  u16* Wqt   = (u16*)take(2097152);
  u16* Wkt   = (u16*)take(2097152);
  u16* Wvt   = (u16*)take(2097152);
  u16* Wot   = (u16*)take(2097152);
  u16* projb = (u16*)take(262144);
  u16* Qb    = (u16*)take(33554432);    // 32768 x 512 bf16
  u16* Kb    = (u16*)take(33554432);
  u16* Vb    = (u16*)take(33554432);
  float* qd  = (float*)take(33554432);  // 32768 x 256 f32
  float* kd  = (float*)take(33554432);
  u16* concat = (u16*)take(33554432);   // 16384 x 1024 bf16
  float* diagq    = (float*)take(131072);
  float* diagk    = (float*)take(131072);
  float* partials = (float*)take(2048);
  float* mxk      = (float*)take(64);
  // peak ws use ~201 MB

  transpose4_kernel<<<dim3(32, 32, 4), dim3(32, 8), 0, stream>>>(Wq, Wk, Wv, Wo,
                                                                 Wqt, Wkt, Wvt, Wot);
  projcvt_kernel<<<128, 256, 0, stream>>>((const float4*)proj, (ushort4*)projb);

  // QKV projections: fp32 A fused conversion, bm on x for XCD L2 locality.
  gemm_bt_kernel<true, true><<<dim3(128, 8), 256, 0, stream>>>(query, Wqt, Qb, bq, 1024, 1024);
  gemm_bt_kernel<true, true><<<dim3(128, 8), 256, 0, stream>>>(key,   Wkt, Kb, bk, 1024, 1024);
  gemm_bt_kernel<true, true><<<dim3(128, 8), 256, 0, stream>>>(value, Wvt, Vb, bv, 1024, 1024);

  diag_kernel<<<16384, 256, 0, stream>>>(Qb, Kb, diagq, diagk);

  gemm_bt_kernel<false, false><<<dim3(256, 2), 256, 0, stream>>>(Qb, projb, qd, nullptr, 512, 256);
  gemm_bt_kernel<false, false><<<dim3(256, 2), 256, 0, stream>>>(Kb, projb, kd, nullptr, 512, 256);

  maxk_part_kernel<<<512, 256, 0, stream>>>(kd, partials);
  maxk_final_kernel<<<8, 64, 0, stream>>>(partials, mxk);

  attn_kernel<<<8192, 256, 0, stream>>>(qd, kd, diagq, diagk, mxk, Vb, concat);

  gemm_bt_kernel<false, false><<<dim3(128, 8), 256, 0, stream>>>(concat, Wot, out, bo, 1024, 1024);
}